// Round 3
// baseline (331.504 us; speedup 1.0000x reference)
//
#include <hip/hip_runtime.h>
#include <stdint.h>

// Problem dims (fixed by the reference)
constexpr int B_ = 2, S_ = 2048, E_ = 1024, H_ = 16, D_ = 64;
constexpr int M_ = B_ * S_;              // 4096 rows

typedef unsigned short u16;
typedef __attribute__((ext_vector_type(8))) short short8;
typedef __attribute__((ext_vector_type(4))) float f32x4;

__device__ __forceinline__ u16 f2bf(float f) {
  uint32_t u = __float_as_uint(f);
  return (u16)((u + 0x7FFFu + ((u >> 16) & 1u)) >> 16);  // RNE
}
// truncation split: hi = trunc16(x), lo = trunc16(x - hi). hi+lo ~ x to 2^-17.
__device__ __forceinline__ void tsplit(float x, u16& hi, u16& lo) {
  const uint32_t u = __float_as_uint(x);
  hi = (u16)(u >> 16);
  const float hif = __uint_as_float(u & 0xFFFF0000u);
  lo = (u16)(__float_as_uint(x - hif) >> 16);
}

// Raw barrier: waits LDS writes (lgkmcnt) but does NOT drain vmcnt — global
// prefetch loads stay in flight across the barrier (T4-style counted waits
// are inserted by the compiler at the consuming ds_write/MFMA).
__device__ __forceinline__ void block_sync() {
  asm volatile("" ::: "memory");
  asm volatile("s_waitcnt lgkmcnt(0)" ::: "memory");
  __builtin_amdgcn_s_barrier();
  asm volatile("" ::: "memory");
}

// ---------------------------------------------------------------------------
// Kernel 0: split fp32 -> (hi, lo) bf16 pair, elementwise (weights).
// ---------------------------------------------------------------------------
__global__ __launch_bounds__(256) void split_f32_kernel(
    const float* __restrict__ src, u16* __restrict__ hi, u16* __restrict__ lo, int n4)
{
  const int i = blockIdx.x * 256 + threadIdx.x;
  if (i >= n4) return;
  const float4 x = ((const float4*)src)[i];
  ushort4 h, l;
  tsplit(x.x, h.x, l.x); tsplit(x.y, h.y, l.y);
  tsplit(x.z, h.z, l.z); tsplit(x.w, h.w, l.w);
  ((ushort4*)hi)[i] = h;
  ((ushort4*)lo)[i] = l;
}

// ---------------------------------------------------------------------------
// Kernel 0b: per-batch scan of key mask -> opos (compact slot j -> orig row s)
// and nk[b] (# unmasked keys).
// ---------------------------------------------------------------------------
__global__ __launch_bounds__(256) void mask_scan_kernel(
    const int* __restrict__ mask, int* __restrict__ opos, int* __restrict__ nk)
{
  __shared__ int tmp[256];
  __shared__ int coff;
  const int b = blockIdx.x, t = threadIdx.x;
  for (int c = t; c < S_; c += 256) opos[b * S_ + c] = 0;  // safe default
  if (t == 0) coff = 0;
  __syncthreads();
  for (int c = 0; c < S_; c += 256) {
    const int m = (mask[b * S_ + c + t] != 0) ? 1 : 0;
    int x = m;
    tmp[t] = x;
    __syncthreads();
#pragma unroll
    for (int off = 1; off < 256; off <<= 1) {
      const int v = (t >= off) ? tmp[t - off] : 0;
      __syncthreads();
      x += v;
      tmp[t] = x;
      __syncthreads();
    }
    const int base = coff;
    if (m) opos[b * S_ + base + x - 1] = c + t;  // scatter: slot -> orig row
    __syncthreads();
    if (t == 255) coff = base + x;
    __syncthreads();
  }
  if (t == 0) nk[b] = coff;
}

// ---------------------------------------------------------------------------
// Kernel 1: QKV projection. v3:
//  - K/V input rows gathered through opos (masked keys never projected);
//    blocks beyond nk exit early (~1/3 less MFMA work).
//  - single-barrier double-buffered LDS k-loop (raw s_barrier, no vmcnt drain;
//    A-prefetch one stage ahead in ping-pong register sets).
//  - B (weights) fragments read DIRECT from global (16B/lane, L2-resident) —
//    no LDS staging for B at all.  LDS = 40 KB (A hi/lo x 2 buffers).
// Tile: 128 rows x 64 cols, 4 waves (2m x 2n), wave = 64x32 (acc[4][2]).
// ---------------------------------------------------------------------------
__global__ __launch_bounds__(256, 3) void gemm_qkv_kernel(
    const float* __restrict__ q, const float* __restrict__ k, const float* __restrict__ v,
    const u16* __restrict__ WHi, const u16* __restrict__ WLo,
    const float* __restrict__ bias,
    const int* __restrict__ Opos, const int* __restrict__ NkArr,
    u16* __restrict__ QpHi, u16* __restrict__ QpLo,
    u16* __restrict__ KpHi, u16* __restrict__ KpLo,
    u16* __restrict__ Vp)
{
  __shared__ __align__(16) short smem[20480];  // 40,960 B
  short* Ah0 = smem;             // [128][40]
  short* Al0 = smem + 5120;
  short* Ah1 = smem + 10240;
  short* Al1 = smem + 15360;

  const int t = threadIdx.x;
  const int m0 = blockIdx.x * 128;
  const int n0g = blockIdx.y * 64;           // global col in [0, 3072)
  const int proj = n0g >> 10;
  const int nloc = n0g & (E_ - 1);
  const bool split = (proj < 2);
  const int bb = m0 >> 11, mloc = m0 & (S_ - 1);
  const int nkb = NkArr[bb];
  if (proj != 0 && mloc >= nkb) return;      // compacted K/V: nothing to do

  const float* A = (proj == 0) ? q : (proj == 1) ? k : v;

  const int w = t >> 6, lane = t & 63;
  const int g = lane >> 4, lc = lane & 15;
  const int wm = w & 1, wn = w >> 1;
  const int sra = t >> 1, sca = (t & 1) * 16; // A staging: 2 thr/row, 16 f32

  // A source row (gathered through opos for K/V)
  int arow;
  if (proj == 0) arow = m0 + sra;
  else arow = bb * S_ + (Opos[bb * S_ + mloc + sra] & (S_ - 1));
  const float* Abp = A + (size_t)arow * E_ + sca;

  // B fragment base (direct global): row = output col, 16B contiguous in k
  const u16* BHrow = WHi + (size_t)(n0g + wn * 32 + lc) * E_ + 8 * g;
  const u16* BLrow = WLo + (size_t)(n0g + wn * 32 + lc) * E_ + 8 * g;

  f32x4 acc[4][2];
#pragma unroll
  for (int i = 0; i < 4; ++i)
#pragma unroll
    for (int j = 0; j < 2; ++j) acc[i][j] = (f32x4){0.f, 0.f, 0.f, 0.f};

  auto loadA = [&](float4* ar, int kk) {
#pragma unroll
    for (int i = 0; i < 4; ++i) ar[i] = *(const float4*)(Abp + kk + 4 * i);
  };
  auto writeA = [&](const float4* ar, short* Ah, short* Al) {
    ushort hh[16], ll[16];
#pragma unroll
    for (int i = 0; i < 4; ++i) {
      tsplit(ar[i].x, hh[4 * i + 0], ll[4 * i + 0]);
      tsplit(ar[i].y, hh[4 * i + 1], ll[4 * i + 1]);
      tsplit(ar[i].z, hh[4 * i + 2], ll[4 * i + 2]);
      tsplit(ar[i].w, hh[4 * i + 3], ll[4 * i + 3]);
    }
    *(short8*)&Ah[sra * 40 + sca]     = *(const short8*)&hh[0];
    *(short8*)&Ah[sra * 40 + sca + 8] = *(const short8*)&hh[8];
    if (split) {
      *(short8*)&Al[sra * 40 + sca]     = *(const short8*)&ll[0];
      *(short8*)&Al[sra * 40 + sca + 8] = *(const short8*)&ll[8];
    }
  };
  auto compute = [&](const short* Ah, const short* Al,
                     short8 bh0, short8 bh1, short8 bl0, short8 bl1) {
    short8 ah[4], al[4];
#pragma unroll
    for (int mt = 0; mt < 4; ++mt) {
      const int ro = (wm * 64 + mt * 16 + lc) * 40 + g * 8;
      ah[mt] = *(const short8*)&Ah[ro];
      if (split) al[mt] = *(const short8*)&Al[ro];
    }
#pragma unroll
    for (int mt = 0; mt < 4; ++mt) {
      f32x4 a0 = acc[mt][0], a1 = acc[mt][1];
      a0 = __builtin_amdgcn_mfma_f32_16x16x32_bf16(ah[mt], bh0, a0, 0, 0, 0);
      a1 = __builtin_amdgcn_mfma_f32_16x16x32_bf16(ah[mt], bh1, a1, 0, 0, 0);
      if (split) {
        a0 = __builtin_amdgcn_mfma_f32_16x16x32_bf16(ah[mt], bl0, a0, 0, 0, 0);
        a0 = __builtin_amdgcn_mfma_f32_16x16x32_bf16(al[mt], bh0, a0, 0, 0, 0);
        a1 = __builtin_amdgcn_mfma_f32_16x16x32_bf16(ah[mt], bl1, a1, 0, 0, 0);
        a1 = __builtin_amdgcn_mfma_f32_16x16x32_bf16(al[mt], bh1, a1, 0, 0, 0);
      }
      acc[mt][0] = a0; acc[mt][1] = a1;
    }
  };

  // ---- pipelined k-loop: unroll-2, one barrier per half-step ----
  float4 arA[4], arB[4];
  short8 b0h0, b0h1, b1h0, b1h1;
  short8 b0l0 = {}, b0l1 = {}, b1l0 = {}, b1l1 = {};
  loadA(arA, 0);
  b0h0 = *(const short8*)(BHrow);
  b0h1 = *(const short8*)(BHrow + 16 * E_);
  if (split) { b0l0 = *(const short8*)(BLrow); b0l1 = *(const short8*)(BLrow + 16 * E_); }

  for (int k0 = 0; k0 < E_; k0 += 64) {
    // half 0: stage set A -> buf0, compute buf0 with b0
    loadA(arB, k0 + 32);
    writeA(arA, Ah0, Al0);
    block_sync();
    b1h0 = *(const short8*)(BHrow + k0 + 32);
    b1h1 = *(const short8*)(BHrow + 16 * E_ + k0 + 32);
    if (split) {
      b1l0 = *(const short8*)(BLrow + k0 + 32);
      b1l1 = *(const short8*)(BLrow + 16 * E_ + k0 + 32);
    }
    compute(Ah0, Al0, b0h0, b0h1, b0l0, b0l1);

    // half 1: stage set B -> buf1, compute buf1 with b1
    const int kn = (k0 + 64 < E_) ? (k0 + 64) : 0;   // clamped (unused on last)
    loadA(arA, kn);
    writeA(arB, Ah1, Al1);
    block_sync();
    b0h0 = *(const short8*)(BHrow + kn);
    b0h1 = *(const short8*)(BHrow + 16 * E_ + kn);
    if (split) {
      b0l0 = *(const short8*)(BLrow + kn);
      b0l1 = *(const short8*)(BLrow + 16 * E_ + kn);
    }
    compute(Ah1, Al1, b1h0, b1h1, b1l0, b1l1);
  }

  // ---- epilogue ----
  float bs[2];
#pragma unroll
  for (int nt = 0; nt < 2; ++nt) bs[nt] = bias[n0g + wn * 32 + nt * 16 + lc];

  if (proj < 2) {
    // block's 64 n-cols = one head; wave covers d-range wn*32..+31.
    // K rows are already compact (input gathered): dense stores; rows >= nk
    // hold garbage but are only read by attn in the masked tail tile.
    u16* Hi = (proj == 0) ? QpHi : KpHi;
    u16* Lo = (proj == 0) ? QpLo : KpLo;
    const int head = nloc >> 6;
    short* T = smem + w * 2560;               // per-wave [64][40] u16
    const int s = (m0 + wm * 64 + lane) & (S_ - 1);
    const size_t rowb = (((size_t)(bb * H_ + head)) * S_ + s) * D_ + wn * 32;
#pragma unroll
    for (int pass = 0; pass < 2; ++pass) {
      __syncthreads();                        // LDS free / prev pass reads done
#pragma unroll
      for (int nt = 0; nt < 2; ++nt)
#pragma unroll
        for (int mt = 0; mt < 4; ++mt)
#pragma unroll
          for (int r = 0; r < 4; ++r) {
            const float val = acc[mt][nt][r] + bs[nt];
            const uint32_t u = __float_as_uint(val);
            u16 x;
            if (pass == 0) x = (u16)(u >> 16);
            else {
              const float hif = __uint_as_float(u & 0xFFFF0000u);
              x = (u16)(__float_as_uint(val - hif) >> 16);
            }
            T[(mt * 16 + g * 4 + r) * 40 + nt * 16 + lc] = (short)x;
          }
      __syncthreads();
      u16* dst = (pass == 0) ? Hi : Lo;
#pragma unroll
      for (int j = 0; j < 4; ++j)
        *(short8*)&dst[rowb + 8 * j] = *(const short8*)&T[lane * 40 + 8 * j];
    }
  } else {
    // V: [B,H,D,S] layout, compact key columns; predicate j < nk (tail stays 0)
#pragma unroll
    for (int mt = 0; mt < 4; ++mt) {
      const int jb = mloc + wm * 64 + mt * 16 + g * 4;
#pragma unroll
      for (int nt = 0; nt < 2; ++nt) {
        const int nE = nloc + wn * 32 + nt * 16 + lc;
        const int h = nE >> 6, d = nE & 63;
        const size_t rb = (((size_t)(bb * H_ + h)) * D_ + d) * S_;
#pragma unroll
        for (int r = 0; r < 4; ++r) {
          if (jb + r < nkb) Vp[rb + jb + r] = f2bf(acc[mt][nt][r] + bs[nt]);
        }
      }
    }
  }
}

// ---------------------------------------------------------------------------
// Kernel 2: MFMA flash attention (unchanged).
// ---------------------------------------------------------------------------
__global__ __launch_bounds__(256, 4) void attn_mfma_kernel(
    const u16* __restrict__ QpHi, const u16* __restrict__ QpLo,
    const u16* __restrict__ KpHi, const u16* __restrict__ KpLo,
    const u16* __restrict__ Vp,
    const int* __restrict__ nkArr,
    u16* __restrict__ AOHi)
{
  __shared__ __align__(16) short sm[18432];  // 36,864 B
  short* Khi = sm;                           // [64][72]
  short* Klo = sm + 4608;                    // [64][72]
  short* Vt  = sm + 9216;                    // [64][72] (d-major)
  short* Pb  = sm + 13824;                   // 4 waves x [16][72]

  const int t = threadIdx.x;
  const int w = t >> 6, lane = t & 63;
  const int g = lane >> 4, lc = lane & 15;
  const int bh = blockIdx.y;
  const int b = bh >> 4, hh = bh & 15;
  const int q0 = blockIdx.x * 64;
  const size_t hb = (size_t)bh * S_ * D_;
  const u16* QgH = QpHi + hb;
  const u16* QgL = QpLo + hb;
  const u16* KgH = KpHi + hb;
  const u16* KgL = KpLo + hb;
  const u16* Vg  = Vp + hb;
  short* Pw = Pb + w * 1152;

  const int nk = nkArr[b];
  const int kend = ((nk + 63) >> 6) << 6;    // tiles of 64 compacted keys

  // ---- Q A-frags direct from global (lane lc = q-row, k = 8g..8g+7) ----
  short8 qh[2], ql[2];
  {
    const size_t base = (size_t)(q0 + 16 * w + lc) * D_ + 8 * g;
    qh[0] = *(const short8*)&QgH[base];
    qh[1] = *(const short8*)&QgH[base + 32];
    ql[0] = *(const short8*)&QgL[base];
    ql[1] = *(const short8*)&QgL[base + 32];
  }

  // ones column in B (n=0): lanes with lc==0 hold bf16(1.0) for all k
  short8 ones8 = {0, 0, 0, 0, 0, 0, 0, 0};
  if (lc == 0) {
    const short o = (short)0x3F80;
    ones8 = (short8){o, o, o, o, o, o, o, o};
  }

  f32x4 O[4];
  f32x4 Ol = (f32x4){0.f, 0.f, 0.f, 0.f};
#pragma unroll
  for (int dt = 0; dt < 4; ++dt) O[dt] = (f32x4){0.f, 0.f, 0.f, 0.f};
  float mst[4] = {-INFINITY, -INFINITY, -INFINITY, -INFINITY};

  const int srow = t >> 2, sc16 = (t & 3) * 16;   // staging: 4 threads/row

  // staging prefetch registers (K hi/lo, V)
  short8 kr[2], lr[2], vr[2];
  kr[0] = *(const short8*)&KgH[srow * D_ + sc16];
  kr[1] = *(const short8*)&KgH[srow * D_ + sc16 + 8];
  lr[0] = *(const short8*)&KgL[srow * D_ + sc16];
  lr[1] = *(const short8*)&KgL[srow * D_ + sc16 + 8];
  vr[0] = *(const short8*)&Vg[srow * S_ + sc16];
  vr[1] = *(const short8*)&Vg[srow * S_ + sc16 + 8];

  for (int kt = 0; kt < kend; kt += 64) {
    __syncthreads();                         // previous tile fully consumed
    *(short8*)&Khi[srow * 72 + sc16]     = kr[0];
    *(short8*)&Khi[srow * 72 + sc16 + 8] = kr[1];
    *(short8*)&Klo[srow * 72 + sc16]     = lr[0];
    *(short8*)&Klo[srow * 72 + sc16 + 8] = lr[1];
    *(short8*)&Vt[srow * 72 + sc16]      = vr[0];
    *(short8*)&Vt[srow * 72 + sc16 + 8]  = vr[1];
    __syncthreads();
    if (kt + 64 < kend) {                    // prefetch next tile
      const int kn = kt + 64;
      kr[0] = *(const short8*)&KgH[(kn + srow) * D_ + sc16];
      kr[1] = *(const short8*)&KgH[(kn + srow) * D_ + sc16 + 8];
      lr[0] = *(const short8*)&KgL[(kn + srow) * D_ + sc16];
      lr[1] = *(const short8*)&KgL[(kn + srow) * D_ + sc16 + 8];
      vr[0] = *(const short8*)&Vg[srow * S_ + kn + sc16];
      vr[1] = *(const short8*)&Vg[srow * S_ + kn + sc16 + 8];
    }

    // ---- scores: S[16q x 64k] ----
    f32x4 sc[4];
#pragma unroll
    for (int kt16 = 0; kt16 < 4; ++kt16) {
      const int ko = (16 * kt16 + lc) * 72 + 8 * g;
      const short8 kh0 = *(const short8*)&Khi[ko];
      const short8 kh1 = *(const short8*)&Khi[ko + 32];
      const short8 kl0 = *(const short8*)&Klo[ko];
      const short8 kl1 = *(const short8*)&Klo[ko + 32];
      f32x4 a = {0.f, 0.f, 0.f, 0.f};
      a = __builtin_amdgcn_mfma_f32_16x16x32_bf16(qh[0], kh0, a, 0, 0, 0);
      a = __builtin_amdgcn_mfma_f32_16x16x32_bf16(qh[1], kh1, a, 0, 0, 0);
      a = __builtin_amdgcn_mfma_f32_16x16x32_bf16(qh[0], kl0, a, 0, 0, 0);
      a = __builtin_amdgcn_mfma_f32_16x16x32_bf16(qh[1], kl1, a, 0, 0, 0);
      a = __builtin_amdgcn_mfma_f32_16x16x32_bf16(ql[0], kh0, a, 0, 0, 0);
      a = __builtin_amdgcn_mfma_f32_16x16x32_bf16(ql[1], kh1, a, 0, 0, 0);
      sc[kt16] = a;
    }

    // ---- tail masking: compacted cols >= nk are padding (garbage K) ----
    if (kt + 64 > nk) {
#pragma unroll
      for (int kt16 = 0; kt16 < 4; ++kt16) {
        if (kt + 16 * kt16 + lc >= nk) {
          sc[kt16][0] = -1e20f; sc[kt16][1] = -1e20f;
          sc[kt16][2] = -1e20f; sc[kt16][3] = -1e20f;
        }
      }
    }

    // ---- online max + exp (max butterfly only; sum comes from MFMA) ----
    float al[4];
#pragma unroll
    for (int r = 0; r < 4; ++r) {
      float vv = fmaxf(fmaxf(sc[0][r], sc[1][r]), fmaxf(sc[2][r], sc[3][r]));
      vv = fmaxf(vv, __shfl_xor(vv, 1));
      vv = fmaxf(vv, __shfl_xor(vv, 2));
      vv = fmaxf(vv, __shfl_xor(vv, 4));
      vv = fmaxf(vv, __shfl_xor(vv, 8));
      const float mn = fmaxf(mst[r], vv);
      al[r] = __expf(mst[r] - mn);           // first tile: exp(-inf)=0
      mst[r] = mn;
    }
#pragma unroll
    for (int kt16 = 0; kt16 < 4; ++kt16) {
#pragma unroll
      for (int r = 0; r < 4; ++r)
        sc[kt16][r] = __expf(sc[kt16][r] - mst[r]);
    }
    const f32x4 alv = {al[0], al[1], al[2], al[3]};
    O[0] *= alv; O[1] *= alv; O[2] *= alv; O[3] *= alv;
    Ol *= alv;
    // P: C-layout regs -> bf16 LDS (A-layout source for PV)
#pragma unroll
    for (int kt16 = 0; kt16 < 4; ++kt16) {
#pragma unroll
      for (int r = 0; r < 4; ++r)
        Pw[(4 * g + r) * 72 + 16 * kt16 + lc] = (short)f2bf(sc[kt16][r]);
    }

    // ---- PV + denominator via ones ----
    short8 pa[2];
    pa[0] = *(const short8*)&Pw[lc * 72 + 8 * g];
    pa[1] = *(const short8*)&Pw[lc * 72 + 32 + 8 * g];
    Ol = __builtin_amdgcn_mfma_f32_16x16x32_bf16(pa[0], ones8, Ol, 0, 0, 0);
    Ol = __builtin_amdgcn_mfma_f32_16x16x32_bf16(pa[1], ones8, Ol, 0, 0, 0);
#pragma unroll
    for (int dt = 0; dt < 4; ++dt) {
      const int vo = (16 * dt + lc) * 72 + 8 * g;
      const short8 vb0 = *(const short8*)&Vt[vo];
      const short8 vb1 = *(const short8*)&Vt[vo + 32];
      O[dt] = __builtin_amdgcn_mfma_f32_16x16x32_bf16(pa[0], vb0, O[dt], 0, 0, 0);
      O[dt] = __builtin_amdgcn_mfma_f32_16x16x32_bf16(pa[1], vb1, O[dt], 0, 0, 0);
    }
  }

  // ---- epilogue: broadcast denominator (col 0 on lanes lc==0), normalize ----
#pragma unroll
  for (int r = 0; r < 4; ++r) {
    const float lv = __shfl(Ol[r], lane & 48);
    const float lir = 1.0f / lv;
    const int qrow = q0 + 16 * w + 4 * g + r;
    const size_t rowb = (size_t)(b * S_ + qrow) * E_ + hh * 64;
#pragma unroll
    for (int dt = 0; dt < 4; ++dt)
      AOHi[rowb + dt * 16 + lc] = f2bf(O[dt][r] * lir);
  }
}

// ---------------------------------------------------------------------------
// Kernel 3: output projection. v2: 64x64 tiles (grid 1024 = 4 blocks/CU),
// single-barrier double-buffered A staging, B direct from global.
// Wave = 64 rows x 16 cols (acc[4]).
// ---------------------------------------------------------------------------
__global__ __launch_bounds__(256) void gemm_out_kernel(
    const u16* __restrict__ AHi,
    const u16* __restrict__ WHi,
    const float* __restrict__ bias, float* __restrict__ out)
{
  __shared__ __align__(16) short smem[5120];   // 2 bufs of [64][40]
  short* A0 = smem;
  short* A1 = smem + 2560;

  const int t = threadIdx.x;
  const int m0 = blockIdx.x * 64;
  const int n0 = blockIdx.y * 64;
  const int w = t >> 6, lane = t & 63;
  const int g = lane >> 4, lc = lane & 15;
  const int srb = t >> 2, scb = (t & 3) * 8;   // staging: 4 thr/row, 8 u16

  const u16* Abp = AHi + (size_t)(m0 + srb) * E_ + scb;
  const u16* Brow = WHi + (size_t)(n0 + w * 16 + lc) * E_ + 8 * g;

  f32x4 acc[4];
#pragma unroll
  for (int i = 0; i < 4; ++i) acc[i] = (f32x4){0.f, 0.f, 0.f, 0.f};

  short8 aA, aB, b0, b1;
  aA = *(const short8*)(Abp);
  b0 = *(const short8*)(Brow);

  for (int k0 = 0; k0 < E_; k0 += 64) {
    // half 0
    aB = *(const short8*)(Abp + k0 + 32);
    *(short8*)&A0[srb * 40 + scb] = aA;
    block_sync();
    b1 = *(const short8*)(Brow + k0 + 32);
    {
      short8 ah[4];
#pragma unroll
      for (int mt = 0; mt < 4; ++mt)
        ah[mt] = *(const short8*)&A0[(mt * 16 + lc) * 40 + g * 8];
#pragma unroll
      for (int mt = 0; mt < 4; ++mt)
        acc[mt] = __builtin_amdgcn_mfma_f32_16x16x32_bf16(ah[mt], b0, acc[mt], 0, 0, 0);
    }
    // half 1
    const int kn = (k0 + 64 < E_) ? (k0 + 64) : 0;
    aA = *(const short8*)(Abp + kn);
    *(short8*)&A1[srb * 40 + scb] = aB;
    block_sync();
    b0 = *(const short8*)(Brow + kn);
    {
      short8 ah[4];
#pragma unroll
      for (int mt = 0; mt < 4; ++mt)
        ah[mt] = *(const short8*)&A1[(mt * 16 + lc) * 40 + g * 8];
#pragma unroll
      for (int mt = 0; mt < 4; ++mt)
        acc[mt] = __builtin_amdgcn_mfma_f32_16x16x32_bf16(ah[mt], b1, acc[mt], 0, 0, 0);
    }
  }

  const int nc = n0 + w * 16 + lc;
  const float bsc = bias[nc];
#pragma unroll
  for (int mt = 0; mt < 4; ++mt) {
#pragma unroll
    for (int r = 0; r < 4; ++r) {
      const int mrow = m0 + mt * 16 + g * 4 + r;
      out[(size_t)mrow * E_ + nc] = acc[mt][r] + bsc;
    }
  }
}

// ---------------------------------------------------------------------------
extern "C" void kernel_launch(void* const* d_in, const int* in_sizes, int n_in,
                              void* d_out, int out_size, void* d_ws, size_t ws_size,
                              hipStream_t stream) {
  const float* q    = (const float*)d_in[0];
  const float* k    = (const float*)d_in[1];
  const float* v    = (const float*)d_in[2];
  const int*   mask = (const int*)d_in[3];
  const float* Wqkv = (const float*)d_in[4];
  const float* bqkv = (const float*)d_in[5];
  const float* Wout = (const float*)d_in[6];
  const float* bout = (const float*)d_in[7];
  float* out = (float*)d_out;

  // Workspace layout (64 MB).
  char* wsb = (char*)d_ws;
  u16* WqkvHi = (u16*)(wsb + 0);          //  6 MB
  u16* WqkvLo = (u16*)(wsb + 6291456);    //  6 MB
  u16* WoutHi = (u16*)(wsb + 12582912);   //  2 MB
  // WoutLo region (2 MB at 14680064) is scratch: split writes it, then the
  // scan kernel reuses the space for opos/nk (stream-ordered, safe).
  int* Opos   = (int*)(wsb + 14680064);   // 16 KB (B*S ints)
  int* Nk     = (int*)(wsb + 14680064 + 16384);  // 8 B
  u16* WoutLo = (u16*)(wsb + 14680064);   // (written then overwritten, unused)
  u16* QpHi   = (u16*)(wsb + 16777216);   //  8 MB
  u16* QpLo   = (u16*)(wsb + 25165824);   //  8 MB
  u16* KpHi   = (u16*)(wsb + 33554432);   //  8 MB
  u16* KpLo   = (u16*)(wsb + 41943040);   //  8 MB
  u16* Vp     = (u16*)(wsb + 50331648);   //  8 MB
  u16* AOHi   = (u16*)(wsb + 58720256);   //  8 MB

  hipLaunchKernelGGL(split_f32_kernel, dim3(3072), dim3(256), 0, stream,
                     Wqkv, WqkvHi, WqkvLo, 786432);
  hipLaunchKernelGGL(split_f32_kernel, dim3(1024), dim3(256), 0, stream,
                     Wout, WoutHi, WoutLo, 262144);
  hipLaunchKernelGGL(mask_scan_kernel, dim3(B_), dim3(256), 0, stream,
                     mask, Opos, Nk);
  // zero V so padded tail columns (>= nk) contribute exact 0 in PV
  hipMemsetAsync(Vp, 0, 8388608, stream);
  hipLaunchKernelGGL(gemm_qkv_kernel, dim3(M_ / 128, 48), dim3(256), 0, stream,
                     q, k, v, WqkvHi, WqkvLo, bqkv, Opos, Nk,
                     QpHi, QpLo, KpHi, KpLo, Vp);
  hipLaunchKernelGGL(attn_mfma_kernel, dim3(S_ / 64, B_ * H_), dim3(256), 0, stream,
                     QpHi, QpLo, KpHi, KpLo, Vp, Nk, AOHi);
  hipLaunchKernelGGL(gemm_out_kernel, dim3(M_ / 64, E_ / 64), dim3(256), 0, stream,
                     AOHi, WoutHi, bout, out);
}

// Round 4
// 296.942 us; speedup vs baseline: 1.1164x; 1.1164x over previous
//
#include <hip/hip_runtime.h>
#include <stdint.h>

// Problem dims (fixed by the reference)
constexpr int B_ = 2, S_ = 2048, E_ = 1024, H_ = 16, D_ = 64;
constexpr int M_ = B_ * S_;              // 4096 rows

typedef unsigned short u16;
typedef __attribute__((ext_vector_type(8))) short short8;
typedef __attribute__((ext_vector_type(4))) float f32x4;

__device__ __forceinline__ u16 f2bf(float f) {
  uint32_t u = __float_as_uint(f);
  return (u16)((u + 0x7FFFu + ((u >> 16) & 1u)) >> 16);  // RNE
}
// truncation split: hi = trunc16(x), lo = trunc16(x - hi). hi+lo ~ x to 2^-17.
__device__ __forceinline__ void tsplit(float x, u16& hi, u16& lo) {
  const uint32_t u = __float_as_uint(x);
  hi = (u16)(u >> 16);
  const float hif = __uint_as_float(u & 0xFFFF0000u);
  lo = (u16)(__float_as_uint(x - hif) >> 16);
}

// ---------------------------------------------------------------------------
// Kernel 0: split fp32 -> (hi, lo) bf16 pair, elementwise (weights).
// ---------------------------------------------------------------------------
__global__ __launch_bounds__(256) void split_f32_kernel(
    const float* __restrict__ src, u16* __restrict__ hi, u16* __restrict__ lo, int n4)
{
  const int i = blockIdx.x * 256 + threadIdx.x;
  if (i >= n4) return;
  const float4 x = ((const float4*)src)[i];
  ushort4 h, l;
  tsplit(x.x, h.x, l.x); tsplit(x.y, h.y, l.y);
  tsplit(x.z, h.z, l.z); tsplit(x.w, h.w, l.w);
  ((ushort4*)hi)[i] = h;
  ((ushort4*)lo)[i] = l;
}

// ---------------------------------------------------------------------------
// Kernel 0b: per-batch scan of key mask -> opos (compact slot j -> orig row s)
// and nk[b] (# unmasked keys).
// ---------------------------------------------------------------------------
__global__ __launch_bounds__(256) void mask_scan_kernel(
    const int* __restrict__ mask, int* __restrict__ opos, int* __restrict__ nk)
{
  __shared__ int tmp[256];
  __shared__ int coff;
  const int b = blockIdx.x, t = threadIdx.x;
  for (int c = t; c < S_; c += 256) opos[b * S_ + c] = 0;  // safe default
  if (t == 0) coff = 0;
  __syncthreads();
  for (int c = 0; c < S_; c += 256) {
    const int m = (mask[b * S_ + c + t] != 0) ? 1 : 0;
    int x = m;
    tmp[t] = x;
    __syncthreads();
#pragma unroll
    for (int off = 1; off < 256; off <<= 1) {
      const int v = (t >= off) ? tmp[t - off] : 0;
      __syncthreads();
      x += v;
      tmp[t] = x;
      __syncthreads();
    }
    const int base = coff;
    if (m) opos[b * S_ + base + x - 1] = c + t;  // scatter: slot -> orig row
    __syncthreads();
    if (t == 255) coff = base + x;
    __syncthreads();
  }
  if (t == 0) nk[b] = coff;
}

// ---------------------------------------------------------------------------
// Kernel 1: QKV projection, split-bf16 MFMA.  Round-2 loop structure
// (two __syncthreads per 32-k step, A & B LDS-staged, register prefetch —
// compiler-scheduled, no inline-asm barriers) + key compaction:
//  - K/V input rows gathered through opos (masked keys never projected);
//    blocks fully beyond nk exit early (~1/3 less MFMA work).
// Tile: 128 rows x 64 cols, 4 waves (2m x 2n), wave = 64x32 (acc[4][2]).
// LDS 30.7 KB.
// ---------------------------------------------------------------------------
__global__ __launch_bounds__(256) void gemm_qkv_kernel(
    const float* __restrict__ q, const float* __restrict__ k, const float* __restrict__ v,
    const u16* __restrict__ WHi, const u16* __restrict__ WLo,
    const float* __restrict__ bias,
    const int* __restrict__ Opos, const int* __restrict__ NkArr,
    u16* __restrict__ QpHi, u16* __restrict__ QpLo,
    u16* __restrict__ KpHi, u16* __restrict__ KpLo,
    u16* __restrict__ Vp)
{
  __shared__ __align__(16) short smem[15360];  // 30,720 B
  short* Ah = smem;            // [128][40]
  short* Al = smem + 5120;     // [128][40]
  short* Bh = smem + 10240;    // [64][40]
  short* Bl = smem + 12800;    // [64][40]

  const int t = threadIdx.x;
  const int m0 = blockIdx.x * 128;
  const int n0g = blockIdx.y * 64;           // global col in [0, 3072)
  const int proj = n0g >> 10;
  const int nloc = n0g & (E_ - 1);
  const bool split = (proj < 2);
  const int bb = m0 >> 11, mloc = m0 & (S_ - 1);
  const int nkb = NkArr[bb];
  if (proj != 0 && mloc >= nkb) return;      // compacted K/V: nothing to do

  const float* A = (proj == 0) ? q : (proj == 1) ? k : v;

  const int w = t >> 6, lane = t & 63;
  const int g = lane >> 4, lc = lane & 15;
  const int wm = w & 1, wn = w >> 1;
  const int sra = t >> 1, sca = (t & 1) * 16; // A staging: 2 thr/row, 16 f32
  const int srb = t >> 2, scb = (t & 3) * 8;  // B staging: 4 thr/row, 8 u16

  // A source row (gathered through opos for K/V)
  int arow;
  if (proj == 0) arow = m0 + sra;
  else arow = bb * S_ + (Opos[bb * S_ + mloc + sra] & (S_ - 1));
  const float* Abp = A + (size_t)arow * E_ + sca;
  const u16* Bhb = WHi + (size_t)(n0g + srb) * E_ + scb;
  const u16* Blb = WLo + (size_t)(n0g + srb) * E_ + scb;

  f32x4 acc[4][2];
#pragma unroll
  for (int i = 0; i < 4; ++i)
#pragma unroll
    for (int j = 0; j < 2; ++j) acc[i][j] = (f32x4){0.f, 0.f, 0.f, 0.f};

  // prefetch registers
  float4 ar[4]; short8 br, cr;
#pragma unroll
  for (int i = 0; i < 4; ++i) ar[i] = *(const float4*)(Abp + 4 * i);
  br = *(const short8*)(Bhb);
  if (split) cr = *(const short8*)(Blb);

  for (int k0 = 0; k0 < E_; k0 += 32) {
    __syncthreads();                 // previous iteration's frag reads done
    // store staged regs -> LDS (A converted hi/lo by truncation split)
#pragma unroll
    for (int i = 0; i < 4; ++i) {
      ushort4 h, l;
      tsplit(ar[i].x, h.x, l.x); tsplit(ar[i].y, h.y, l.y);
      tsplit(ar[i].z, h.z, l.z); tsplit(ar[i].w, h.w, l.w);
      *(ushort4*)&Ah[sra * 40 + sca + 4 * i] = h;
      if (split) *(ushort4*)&Al[sra * 40 + sca + 4 * i] = l;
    }
    *(short8*)&Bh[srb * 40 + scb] = br;
    if (split) *(short8*)&Bl[srb * 40 + scb] = cr;
    __syncthreads();
    // prefetch next K-step (latency hidden behind frag reads + MFMA)
    if (k0 + 32 < E_) {
#pragma unroll
      for (int i = 0; i < 4; ++i) ar[i] = *(const float4*)(Abp + k0 + 32 + 4 * i);
      br = *(const short8*)(Bhb + k0 + 32);
      if (split) cr = *(const short8*)(Blb + k0 + 32);
    }

    short8 ah[4], al[4], bh[2], bl[2];
#pragma unroll
    for (int mt = 0; mt < 4; ++mt) {
      const int ro = (wm * 64 + mt * 16 + lc) * 40 + g * 8;
      ah[mt] = *(const short8*)&Ah[ro];
      if (split) al[mt] = *(const short8*)&Al[ro];
    }
#pragma unroll
    for (int nt = 0; nt < 2; ++nt) {
      const int ro = (wn * 32 + nt * 16 + lc) * 40 + g * 8;
      bh[nt] = *(const short8*)&Bh[ro];
      if (split) bl[nt] = *(const short8*)&Bl[ro];
    }
#pragma unroll
    for (int mt = 0; mt < 4; ++mt)
#pragma unroll
      for (int nt = 0; nt < 2; ++nt) {
        f32x4 a = acc[mt][nt];
        a = __builtin_amdgcn_mfma_f32_16x16x32_bf16(ah[mt], bh[nt], a, 0, 0, 0);
        if (split) {
          a = __builtin_amdgcn_mfma_f32_16x16x32_bf16(ah[mt], bl[nt], a, 0, 0, 0);
          a = __builtin_amdgcn_mfma_f32_16x16x32_bf16(al[mt], bh[nt], a, 0, 0, 0);
        }
        acc[mt][nt] = a;
      }
  }

  // ---- epilogue ----
  float bs[2];
#pragma unroll
  for (int nt = 0; nt < 2; ++nt) bs[nt] = bias[n0g + wn * 32 + nt * 16 + lc];

  if (proj < 2) {
    // block's 64 n-cols = one head; wave covers d-range wn*32..+31.
    // K rows are already compact (input gathered): dense stores; rows >= nk
    // hold junk but attn masks cols >= nk before exp.
    u16* Hi = (proj == 0) ? QpHi : KpHi;
    u16* Lo = (proj == 0) ? QpLo : KpLo;
    const int head = nloc >> 6;
    short* T = smem + w * 2560;               // per-wave [64][40] u16
    const int s = (m0 + wm * 64 + lane) & (S_ - 1);
    const size_t rowb = (((size_t)(bb * H_ + head)) * S_ + s) * D_ + wn * 32;
#pragma unroll
    for (int pass = 0; pass < 2; ++pass) {
      __syncthreads();                        // LDS free / prev pass reads done
#pragma unroll
      for (int nt = 0; nt < 2; ++nt)
#pragma unroll
        for (int mt = 0; mt < 4; ++mt)
#pragma unroll
          for (int r = 0; r < 4; ++r) {
            const float val = acc[mt][nt][r] + bs[nt];
            const uint32_t u = __float_as_uint(val);
            u16 x;
            if (pass == 0) x = (u16)(u >> 16);
            else {
              const float hif = __uint_as_float(u & 0xFFFF0000u);
              x = (u16)(__float_as_uint(val - hif) >> 16);
            }
            T[(mt * 16 + g * 4 + r) * 40 + nt * 16 + lc] = (short)x;
          }
      __syncthreads();
      u16* dst = (pass == 0) ? Hi : Lo;
#pragma unroll
      for (int j = 0; j < 4; ++j)
        *(short8*)&dst[rowb + 8 * j] = *(const short8*)&T[lane * 40 + 8 * j];
    }
  } else {
    // V: [B,H,D,S] layout, compact key columns; predicate j < nk (tail stays 0)
#pragma unroll
    for (int mt = 0; mt < 4; ++mt) {
      const int jb = mloc + wm * 64 + mt * 16 + g * 4;
#pragma unroll
      for (int nt = 0; nt < 2; ++nt) {
        const int nE = nloc + wn * 32 + nt * 16 + lc;
        const int h = nE >> 6, d = nE & 63;
        const size_t rb = (((size_t)(bb * H_ + h)) * D_ + d) * S_;
#pragma unroll
        for (int r = 0; r < 4; ++r) {
          if (jb + r < nkb) Vp[rb + jb + r] = f2bf(acc[mt][nt][r] + bs[nt]);
        }
      }
    }
  }
}

// ---------------------------------------------------------------------------
// Kernel 2: MFMA flash attention (unchanged).
// ---------------------------------------------------------------------------
__global__ __launch_bounds__(256, 4) void attn_mfma_kernel(
    const u16* __restrict__ QpHi, const u16* __restrict__ QpLo,
    const u16* __restrict__ KpHi, const u16* __restrict__ KpLo,
    const u16* __restrict__ Vp,
    const int* __restrict__ nkArr,
    u16* __restrict__ AOHi)
{
  __shared__ __align__(16) short sm[18432];  // 36,864 B
  short* Khi = sm;                           // [64][72]
  short* Klo = sm + 4608;                    // [64][72]
  short* Vt  = sm + 9216;                    // [64][72] (d-major)
  short* Pb  = sm + 13824;                   // 4 waves x [16][72]

  const int t = threadIdx.x;
  const int w = t >> 6, lane = t & 63;
  const int g = lane >> 4, lc = lane & 15;
  const int bh = blockIdx.y;
  const int b = bh >> 4, hh = bh & 15;
  const int q0 = blockIdx.x * 64;
  const size_t hb = (size_t)bh * S_ * D_;
  const u16* QgH = QpHi + hb;
  const u16* QgL = QpLo + hb;
  const u16* KgH = KpHi + hb;
  const u16* KgL = KpLo + hb;
  const u16* Vg  = Vp + hb;
  short* Pw = Pb + w * 1152;

  const int nk = nkArr[b];
  const int kend = ((nk + 63) >> 6) << 6;    // tiles of 64 compacted keys

  // ---- Q A-frags direct from global (lane lc = q-row, k = 8g..8g+7) ----
  short8 qh[2], ql[2];
  {
    const size_t base = (size_t)(q0 + 16 * w + lc) * D_ + 8 * g;
    qh[0] = *(const short8*)&QgH[base];
    qh[1] = *(const short8*)&QgH[base + 32];
    ql[0] = *(const short8*)&QgL[base];
    ql[1] = *(const short8*)&QgL[base + 32];
  }

  // ones column in B (n=0): lanes with lc==0 hold bf16(1.0) for all k
  short8 ones8 = {0, 0, 0, 0, 0, 0, 0, 0};
  if (lc == 0) {
    const short o = (short)0x3F80;
    ones8 = (short8){o, o, o, o, o, o, o, o};
  }

  f32x4 O[4];
  f32x4 Ol = (f32x4){0.f, 0.f, 0.f, 0.f};
#pragma unroll
  for (int dt = 0; dt < 4; ++dt) O[dt] = (f32x4){0.f, 0.f, 0.f, 0.f};
  float mst[4] = {-INFINITY, -INFINITY, -INFINITY, -INFINITY};

  const int srow = t >> 2, sc16 = (t & 3) * 16;   // staging: 4 threads/row

  // staging prefetch registers (K hi/lo, V)
  short8 kr[2], lr[2], vr[2];
  kr[0] = *(const short8*)&KgH[srow * D_ + sc16];
  kr[1] = *(const short8*)&KgH[srow * D_ + sc16 + 8];
  lr[0] = *(const short8*)&KgL[srow * D_ + sc16];
  lr[1] = *(const short8*)&KgL[srow * D_ + sc16 + 8];
  vr[0] = *(const short8*)&Vg[srow * S_ + sc16];
  vr[1] = *(const short8*)&Vg[srow * S_ + sc16 + 8];

  for (int kt = 0; kt < kend; kt += 64) {
    __syncthreads();                         // previous tile fully consumed
    *(short8*)&Khi[srow * 72 + sc16]     = kr[0];
    *(short8*)&Khi[srow * 72 + sc16 + 8] = kr[1];
    *(short8*)&Klo[srow * 72 + sc16]     = lr[0];
    *(short8*)&Klo[srow * 72 + sc16 + 8] = lr[1];
    *(short8*)&Vt[srow * 72 + sc16]      = vr[0];
    *(short8*)&Vt[srow * 72 + sc16 + 8]  = vr[1];
    __syncthreads();
    if (kt + 64 < kend) {                    // prefetch next tile
      const int kn = kt + 64;
      kr[0] = *(const short8*)&KgH[(kn + srow) * D_ + sc16];
      kr[1] = *(const short8*)&KgH[(kn + srow) * D_ + sc16 + 8];
      lr[0] = *(const short8*)&KgL[(kn + srow) * D_ + sc16];
      lr[1] = *(const short8*)&KgL[(kn + srow) * D_ + sc16 + 8];
      vr[0] = *(const short8*)&Vg[srow * S_ + kn + sc16];
      vr[1] = *(const short8*)&Vg[srow * S_ + kn + sc16 + 8];
    }

    // ---- scores: S[16q x 64k] ----
    f32x4 sc[4];
#pragma unroll
    for (int kt16 = 0; kt16 < 4; ++kt16) {
      const int ko = (16 * kt16 + lc) * 72 + 8 * g;
      const short8 kh0 = *(const short8*)&Khi[ko];
      const short8 kh1 = *(const short8*)&Khi[ko + 32];
      const short8 kl0 = *(const short8*)&Klo[ko];
      const short8 kl1 = *(const short8*)&Klo[ko + 32];
      f32x4 a = {0.f, 0.f, 0.f, 0.f};
      a = __builtin_amdgcn_mfma_f32_16x16x32_bf16(qh[0], kh0, a, 0, 0, 0);
      a = __builtin_amdgcn_mfma_f32_16x16x32_bf16(qh[1], kh1, a, 0, 0, 0);
      a = __builtin_amdgcn_mfma_f32_16x16x32_bf16(qh[0], kl0, a, 0, 0, 0);
      a = __builtin_amdgcn_mfma_f32_16x16x32_bf16(qh[1], kl1, a, 0, 0, 0);
      a = __builtin_amdgcn_mfma_f32_16x16x32_bf16(ql[0], kh0, a, 0, 0, 0);
      a = __builtin_amdgcn_mfma_f32_16x16x32_bf16(ql[1], kh1, a, 0, 0, 0);
      sc[kt16] = a;
    }

    // ---- tail masking: compacted cols >= nk are padding (garbage K) ----
    if (kt + 64 > nk) {
#pragma unroll
      for (int kt16 = 0; kt16 < 4; ++kt16) {
        if (kt + 16 * kt16 + lc >= nk) {
          sc[kt16][0] = -1e20f; sc[kt16][1] = -1e20f;
          sc[kt16][2] = -1e20f; sc[kt16][3] = -1e20f;
        }
      }
    }

    // ---- online max + exp (max butterfly only; sum comes from MFMA) ----
    float al[4];
#pragma unroll
    for (int r = 0; r < 4; ++r) {
      float vv = fmaxf(fmaxf(sc[0][r], sc[1][r]), fmaxf(sc[2][r], sc[3][r]));
      vv = fmaxf(vv, __shfl_xor(vv, 1));
      vv = fmaxf(vv, __shfl_xor(vv, 2));
      vv = fmaxf(vv, __shfl_xor(vv, 4));
      vv = fmaxf(vv, __shfl_xor(vv, 8));
      const float mn = fmaxf(mst[r], vv);
      al[r] = __expf(mst[r] - mn);           // first tile: exp(-inf)=0
      mst[r] = mn;
    }
#pragma unroll
    for (int kt16 = 0; kt16 < 4; ++kt16) {
#pragma unroll
      for (int r = 0; r < 4; ++r)
        sc[kt16][r] = __expf(sc[kt16][r] - mst[r]);
    }
    const f32x4 alv = {al[0], al[1], al[2], al[3]};
    O[0] *= alv; O[1] *= alv; O[2] *= alv; O[3] *= alv;
    Ol *= alv;
    // P: C-layout regs -> bf16 LDS (A-layout source for PV)
#pragma unroll
    for (int kt16 = 0; kt16 < 4; ++kt16) {
#pragma unroll
      for (int r = 0; r < 4; ++r)
        Pw[(4 * g + r) * 72 + 16 * kt16 + lc] = (short)f2bf(sc[kt16][r]);
    }

    // ---- PV + denominator via ones ----
    short8 pa[2];
    pa[0] = *(const short8*)&Pw[lc * 72 + 8 * g];
    pa[1] = *(const short8*)&Pw[lc * 72 + 32 + 8 * g];
    Ol = __builtin_amdgcn_mfma_f32_16x16x32_bf16(pa[0], ones8, Ol, 0, 0, 0);
    Ol = __builtin_amdgcn_mfma_f32_16x16x32_bf16(pa[1], ones8, Ol, 0, 0, 0);
#pragma unroll
    for (int dt = 0; dt < 4; ++dt) {
      const int vo = (16 * dt + lc) * 72 + 8 * g;
      const short8 vb0 = *(const short8*)&Vt[vo];
      const short8 vb1 = *(const short8*)&Vt[vo + 32];
      O[dt] = __builtin_amdgcn_mfma_f32_16x16x32_bf16(pa[0], vb0, O[dt], 0, 0, 0);
      O[dt] = __builtin_amdgcn_mfma_f32_16x16x32_bf16(pa[1], vb1, O[dt], 0, 0, 0);
    }
  }

  // ---- epilogue: broadcast denominator (col 0 on lanes lc==0), normalize ----
#pragma unroll
  for (int r = 0; r < 4; ++r) {
    const float lv = __shfl(Ol[r], lane & 48);
    const float lir = 1.0f / lv;
    const int qrow = q0 + 16 * w + 4 * g + r;
    const size_t rowb = (size_t)(b * S_ + qrow) * E_ + hh * 64;
#pragma unroll
    for (int dt = 0; dt < 4; ++dt)
      AOHi[rowb + dt * 16 + lc] = f2bf(O[dt][r] * lir);
  }
}

// ---------------------------------------------------------------------------
// Kernel 3: output projection. v3: 64x64 tiles (grid 64x16 = 1024 blocks =
// 4 blocks/CU), round-2-style loop: A & B LDS-staged, two __syncthreads per
// 32-k step, register prefetch, no inline-asm barriers.
// 4 waves (2m x 2n), wave = 32x32 (acc[2][2]).  LDS 20.5 KB.
// ---------------------------------------------------------------------------
__global__ __launch_bounds__(256) void gemm_out_kernel(
    const u16* __restrict__ AHi,
    const u16* __restrict__ WHi,
    const float* __restrict__ bias, float* __restrict__ out)
{
  __shared__ __align__(16) short smem[5120];   // A[64][40] + B[64][40]
  short* Ah = smem;
  short* Bh = smem + 2560;

  const int t = threadIdx.x;
  const int m0 = blockIdx.x * 64;
  const int n0 = blockIdx.y * 64;
  const int w = t >> 6, lane = t & 63;
  const int g = lane >> 4, lc = lane & 15;
  const int wm = w & 1, wn = w >> 1;
  const int sr = t >> 2, sc = (t & 3) * 8;     // staging: 4 thr/row, 8 u16

  const u16* Ahb = AHi + (size_t)(m0 + sr) * E_ + sc;
  const u16* Bhb = WHi + (size_t)(n0 + sr) * E_ + sc;

  f32x4 acc[2][2];
#pragma unroll
  for (int i = 0; i < 2; ++i)
#pragma unroll
    for (int j = 0; j < 2; ++j) acc[i][j] = (f32x4){0.f, 0.f, 0.f, 0.f};

  short8 arr, brr;
  arr = *(const short8*)(Ahb);
  brr = *(const short8*)(Bhb);

  for (int k0 = 0; k0 < E_; k0 += 32) {
    __syncthreads();
    *(short8*)&Ah[sr * 40 + sc] = arr;
    *(short8*)&Bh[sr * 40 + sc] = brr;
    __syncthreads();
    if (k0 + 32 < E_) {
      arr = *(const short8*)(Ahb + k0 + 32);
      brr = *(const short8*)(Bhb + k0 + 32);
    }

    short8 ah[2], bh[2];
#pragma unroll
    for (int mt = 0; mt < 2; ++mt)
      ah[mt] = *(const short8*)&Ah[(wm * 32 + mt * 16 + lc) * 40 + g * 8];
#pragma unroll
    for (int nt = 0; nt < 2; ++nt)
      bh[nt] = *(const short8*)&Bh[(wn * 32 + nt * 16 + lc) * 40 + g * 8];
#pragma unroll
    for (int mt = 0; mt < 2; ++mt)
#pragma unroll
      for (int nt = 0; nt < 2; ++nt)
        acc[mt][nt] = __builtin_amdgcn_mfma_f32_16x16x32_bf16(ah[mt], bh[nt], acc[mt][nt], 0, 0, 0);
  }

  float bs[2];
#pragma unroll
  for (int nt = 0; nt < 2; ++nt) bs[nt] = bias[n0 + wn * 32 + nt * 16 + lc];
#pragma unroll
  for (int nt = 0; nt < 2; ++nt) {
    const int nc = n0 + wn * 32 + nt * 16 + lc;
#pragma unroll
    for (int mt = 0; mt < 2; ++mt) {
#pragma unroll
      for (int r = 0; r < 4; ++r) {
        const int mrow = m0 + wm * 32 + mt * 16 + g * 4 + r;
        out[(size_t)mrow * E_ + nc] = acc[mt][nt][r] + bs[nt];
      }
    }
  }
}

// ---------------------------------------------------------------------------
extern "C" void kernel_launch(void* const* d_in, const int* in_sizes, int n_in,
                              void* d_out, int out_size, void* d_ws, size_t ws_size,
                              hipStream_t stream) {
  const float* q    = (const float*)d_in[0];
  const float* k    = (const float*)d_in[1];
  const float* v    = (const float*)d_in[2];
  const int*   mask = (const int*)d_in[3];
  const float* Wqkv = (const float*)d_in[4];
  const float* bqkv = (const float*)d_in[5];
  const float* Wout = (const float*)d_in[6];
  const float* bout = (const float*)d_in[7];
  float* out = (float*)d_out;

  // Workspace layout (64 MB).
  char* wsb = (char*)d_ws;
  u16* WqkvHi = (u16*)(wsb + 0);          //  6 MB
  u16* WqkvLo = (u16*)(wsb + 6291456);    //  6 MB
  u16* WoutHi = (u16*)(wsb + 12582912);   //  2 MB
  // WoutLo region (2 MB at 14680064) is scratch: split writes it, then the
  // scan kernel reuses the space for opos/nk (stream-ordered, safe).
  int* Opos   = (int*)(wsb + 14680064);   // 16 KB (B*S ints)
  int* Nk     = (int*)(wsb + 14680064 + 16384);  // 8 B
  u16* WoutLo = (u16*)(wsb + 14680064);   // (written then overwritten, unused)
  u16* QpHi   = (u16*)(wsb + 16777216);   //  8 MB
  u16* QpLo   = (u16*)(wsb + 25165824);   //  8 MB
  u16* KpHi   = (u16*)(wsb + 33554432);   //  8 MB
  u16* KpLo   = (u16*)(wsb + 41943040);   //  8 MB
  u16* Vp     = (u16*)(wsb + 50331648);   //  8 MB
  u16* AOHi   = (u16*)(wsb + 58720256);   //  8 MB

  hipLaunchKernelGGL(split_f32_kernel, dim3(3072), dim3(256), 0, stream,
                     Wqkv, WqkvHi, WqkvLo, 786432);
  hipLaunchKernelGGL(split_f32_kernel, dim3(1024), dim3(256), 0, stream,
                     Wout, WoutHi, WoutLo, 262144);
  hipLaunchKernelGGL(mask_scan_kernel, dim3(B_), dim3(256), 0, stream,
                     mask, Opos, Nk);
  // zero V so padded tail columns (>= nk) contribute exact 0 in PV
  hipMemsetAsync(Vp, 0, 8388608, stream);
  hipLaunchKernelGGL(gemm_qkv_kernel, dim3(M_ / 128, 48), dim3(256), 0, stream,
                     q, k, v, WqkvHi, WqkvLo, bqkv, Opos, Nk,
                     QpHi, QpLo, KpHi, KpLo, Vp);
  hipLaunchKernelGGL(attn_mfma_kernel, dim3(S_ / 64, B_ * H_), dim3(256), 0, stream,
                     QpHi, QpLo, KpHi, KpLo, Vp, Nk, AOHi);
  hipLaunchKernelGGL(gemm_out_kernel, dim3(M_ / 64, E_ / 64), dim3(256), 0, stream,
                     AOHi, WoutHi, bout, out);
}

// Round 5
// 292.858 us; speedup vs baseline: 1.1320x; 1.0139x over previous
//
#include <hip/hip_runtime.h>
#include <stdint.h>

// Problem dims (fixed by the reference)
constexpr int B_ = 2, S_ = 2048, E_ = 1024, H_ = 16, D_ = 64;
constexpr int M_ = B_ * S_;              // 4096 rows

typedef unsigned short u16;
typedef __attribute__((ext_vector_type(8))) short short8;
typedef __attribute__((ext_vector_type(4))) float f32x4;

__device__ __forceinline__ u16 f2bf(float f) {
  uint32_t u = __float_as_uint(f);
  return (u16)((u + 0x7FFFu + ((u >> 16) & 1u)) >> 16);  // RNE
}
// truncation split: hi = trunc16(x), lo = trunc16(x - hi). hi+lo ~ x to 2^-17.
__device__ __forceinline__ void tsplit(float x, u16& hi, u16& lo) {
  const uint32_t u = __float_as_uint(x);
  hi = (u16)(u >> 16);
  const float hif = __uint_as_float(u & 0xFFFF0000u);
  lo = (u16)(__float_as_uint(x - hif) >> 16);
}

// ---------------------------------------------------------------------------
// Kernel 0: split fp32 -> (hi, lo) bf16 pair, elementwise (weights).
// ---------------------------------------------------------------------------
__global__ __launch_bounds__(256) void split_f32_kernel(
    const float* __restrict__ src, u16* __restrict__ hi, u16* __restrict__ lo, int n4)
{
  const int i = blockIdx.x * 256 + threadIdx.x;
  if (i >= n4) return;
  const float4 x = ((const float4*)src)[i];
  ushort4 h, l;
  tsplit(x.x, h.x, l.x); tsplit(x.y, h.y, l.y);
  tsplit(x.z, h.z, l.z); tsplit(x.w, h.w, l.w);
  ((ushort4*)hi)[i] = h;
  ((ushort4*)lo)[i] = l;
}

// ---------------------------------------------------------------------------
// Kernel 0b: per-batch scan of key mask -> opos (compact slot j -> orig row s)
// and nk[b] (# unmasked keys).
// ---------------------------------------------------------------------------
__global__ __launch_bounds__(256) void mask_scan_kernel(
    const int* __restrict__ mask, int* __restrict__ opos, int* __restrict__ nk)
{
  __shared__ int tmp[256];
  __shared__ int coff;
  const int b = blockIdx.x, t = threadIdx.x;
  for (int c = t; c < S_; c += 256) opos[b * S_ + c] = 0;  // safe default
  if (t == 0) coff = 0;
  __syncthreads();
  for (int c = 0; c < S_; c += 256) {
    const int m = (mask[b * S_ + c + t] != 0) ? 1 : 0;
    int x = m;
    tmp[t] = x;
    __syncthreads();
#pragma unroll
    for (int off = 1; off < 256; off <<= 1) {
      const int v = (t >= off) ? tmp[t - off] : 0;
      __syncthreads();
      x += v;
      tmp[t] = x;
      __syncthreads();
    }
    const int base = coff;
    if (m) opos[b * S_ + base + x - 1] = c + t;  // scatter: slot -> orig row
    __syncthreads();
    if (t == 255) coff = base + x;
    __syncthreads();
  }
  if (t == 0) nk[b] = coff;
}

// ---------------------------------------------------------------------------
// Kernel 1: QKV projection, split-bf16 MFMA + key compaction.
// v5: distance-2 register prefetch (ping-pong reg sets; loads for step t+2
// issued at step t -> ~2 compute-phases of latency cover), A staging stores
// packed as b128. Single LDS buffer, two __syncthreads per 32-k step
// (compiler-scheduled; proven best structure).
// Tile: 128 rows x 64 cols, 4 waves (2m x 2n), wave = 64x32 (acc[4][2]).
// LDS 30.7 KB.
// ---------------------------------------------------------------------------
__global__ __launch_bounds__(256) void gemm_qkv_kernel(
    const float* __restrict__ q, const float* __restrict__ k, const float* __restrict__ v,
    const u16* __restrict__ WHi, const u16* __restrict__ WLo,
    const float* __restrict__ bias,
    const int* __restrict__ Opos, const int* __restrict__ NkArr,
    u16* __restrict__ QpHi, u16* __restrict__ QpLo,
    u16* __restrict__ KpHi, u16* __restrict__ KpLo,
    u16* __restrict__ Vp)
{
  __shared__ __align__(16) short smem[15360];  // 30,720 B
  short* Ah = smem;            // [128][40]
  short* Al = smem + 5120;     // [128][40]
  short* Bh = smem + 10240;    // [64][40]
  short* Bl = smem + 12800;    // [64][40]

  const int t = threadIdx.x;
  const int m0 = blockIdx.x * 128;
  const int n0g = blockIdx.y * 64;           // global col in [0, 3072)
  const int proj = n0g >> 10;
  const int nloc = n0g & (E_ - 1);
  const bool split = (proj < 2);
  const int bb = m0 >> 11, mloc = m0 & (S_ - 1);
  const int nkb = NkArr[bb];
  if (proj != 0 && mloc >= nkb) return;      // compacted K/V: nothing to do

  const float* A = (proj == 0) ? q : (proj == 1) ? k : v;

  const int w = t >> 6, lane = t & 63;
  const int g = lane >> 4, lc = lane & 15;
  const int wm = w & 1, wn = w >> 1;
  const int sra = t >> 1, sca = (t & 1) * 16; // A staging: 2 thr/row, 16 f32
  const int srb = t >> 2, scb = (t & 3) * 8;  // B staging: 4 thr/row, 8 u16

  // A source row (gathered through opos for K/V)
  int arow;
  if (proj == 0) arow = m0 + sra;
  else arow = bb * S_ + (Opos[bb * S_ + mloc + sra] & (S_ - 1));
  const float* Abp = A + (size_t)arow * E_ + sca;
  const u16* Bhb = WHi + (size_t)(n0g + srb) * E_ + scb;
  const u16* Blb = WLo + (size_t)(n0g + srb) * E_ + scb;

  f32x4 acc[4][2];
#pragma unroll
  for (int i = 0; i < 4; ++i)
#pragma unroll
    for (int j = 0; j < 2; ++j) acc[i][j] = (f32x4){0.f, 0.f, 0.f, 0.f};

  auto loadA = [&](float4* ar, int kk) {
#pragma unroll
    for (int i = 0; i < 4; ++i) ar[i] = *(const float4*)(Abp + kk + 4 * i);
  };
  auto writeA = [&](const float4* ar) {
    ushort hh[16], ll[16];
#pragma unroll
    for (int i = 0; i < 4; ++i) {
      tsplit(ar[i].x, hh[4 * i + 0], ll[4 * i + 0]);
      tsplit(ar[i].y, hh[4 * i + 1], ll[4 * i + 1]);
      tsplit(ar[i].z, hh[4 * i + 2], ll[4 * i + 2]);
      tsplit(ar[i].w, hh[4 * i + 3], ll[4 * i + 3]);
    }
    *(short8*)&Ah[sra * 40 + sca]     = *(const short8*)&hh[0];
    *(short8*)&Ah[sra * 40 + sca + 8] = *(const short8*)&hh[8];
    if (split) {
      *(short8*)&Al[sra * 40 + sca]     = *(const short8*)&ll[0];
      *(short8*)&Al[sra * 40 + sca + 8] = *(const short8*)&ll[8];
    }
  };

  // distance-2 prefetch: reg sets 0/1 hold steps t, t+1
  float4 arP[2][4];
  short8 brP[2], crP[2] = {};
  loadA(arP[0], 0);
  loadA(arP[1], 32);
  brP[0] = *(const short8*)(Bhb);
  brP[1] = *(const short8*)(Bhb + 32);
  if (split) {
    crP[0] = *(const short8*)(Blb);
    crP[1] = *(const short8*)(Blb + 32);
  }

#pragma unroll 2
  for (int k0 = 0; k0 < E_; k0 += 32) {
    const int p = (k0 >> 5) & 1;
    __syncthreads();                 // previous iteration's frag reads done
    writeA(arP[p]);
    *(short8*)&Bh[srb * 40 + scb] = brP[p];
    if (split) *(short8*)&Bl[srb * 40 + scb] = crP[p];
    __syncthreads();
    // refill reg set p for step t+2 (consumed after 2 more compute phases)
    {
      const int kk = (k0 + 64) & (E_ - 1);   // wraps harmlessly on last steps
      loadA(arP[p], kk);
      brP[p] = *(const short8*)(Bhb + kk);
      if (split) crP[p] = *(const short8*)(Blb + kk);
    }

    short8 ah[4], al[4], bh[2], bl[2];
#pragma unroll
    for (int mt = 0; mt < 4; ++mt) {
      const int ro = (wm * 64 + mt * 16 + lc) * 40 + g * 8;
      ah[mt] = *(const short8*)&Ah[ro];
      if (split) al[mt] = *(const short8*)&Al[ro];
    }
#pragma unroll
    for (int nt = 0; nt < 2; ++nt) {
      const int ro = (wn * 32 + nt * 16 + lc) * 40 + g * 8;
      bh[nt] = *(const short8*)&Bh[ro];
      if (split) bl[nt] = *(const short8*)&Bl[ro];
    }
#pragma unroll
    for (int mt = 0; mt < 4; ++mt)
#pragma unroll
      for (int nt = 0; nt < 2; ++nt) {
        f32x4 a = acc[mt][nt];
        a = __builtin_amdgcn_mfma_f32_16x16x32_bf16(ah[mt], bh[nt], a, 0, 0, 0);
        if (split) {
          a = __builtin_amdgcn_mfma_f32_16x16x32_bf16(ah[mt], bl[nt], a, 0, 0, 0);
          a = __builtin_amdgcn_mfma_f32_16x16x32_bf16(al[mt], bh[nt], a, 0, 0, 0);
        }
        acc[mt][nt] = a;
      }
  }

  // ---- epilogue ----
  float bs[2];
#pragma unroll
  for (int nt = 0; nt < 2; ++nt) bs[nt] = bias[n0g + wn * 32 + nt * 16 + lc];

  if (proj < 2) {
    // block's 64 n-cols = one head; wave covers d-range wn*32..+31.
    // K rows are already compact (input gathered): dense stores; rows >= nk
    // hold junk but attn masks cols >= nk before exp.
    u16* Hi = (proj == 0) ? QpHi : KpHi;
    u16* Lo = (proj == 0) ? QpLo : KpLo;
    const int head = nloc >> 6;
    short* T = smem + w * 2560;               // per-wave [64][40] u16
    const int s = (m0 + wm * 64 + lane) & (S_ - 1);
    const size_t rowb = (((size_t)(bb * H_ + head)) * S_ + s) * D_ + wn * 32;
#pragma unroll
    for (int pass = 0; pass < 2; ++pass) {
      __syncthreads();                        // LDS free / prev pass reads done
#pragma unroll
      for (int nt = 0; nt < 2; ++nt)
#pragma unroll
        for (int mt = 0; mt < 4; ++mt)
#pragma unroll
          for (int r = 0; r < 4; ++r) {
            const float val = acc[mt][nt][r] + bs[nt];
            const uint32_t u = __float_as_uint(val);
            u16 x;
            if (pass == 0) x = (u16)(u >> 16);
            else {
              const float hif = __uint_as_float(u & 0xFFFF0000u);
              x = (u16)(__float_as_uint(val - hif) >> 16);
            }
            T[(mt * 16 + g * 4 + r) * 40 + nt * 16 + lc] = (short)x;
          }
      __syncthreads();
      u16* dst = (pass == 0) ? Hi : Lo;
#pragma unroll
      for (int j = 0; j < 4; ++j)
        *(short8*)&dst[rowb + 8 * j] = *(const short8*)&T[lane * 40 + 8 * j];
    }
  } else {
    // V: [B,H,D,S] layout, compact key columns; predicate j < nk (tail stays 0)
#pragma unroll
    for (int mt = 0; mt < 4; ++mt) {
      const int jb = mloc + wm * 64 + mt * 16 + g * 4;
#pragma unroll
      for (int nt = 0; nt < 2; ++nt) {
        const int nE = nloc + wn * 32 + nt * 16 + lc;
        const int h = nE >> 6, d = nE & 63;
        const size_t rb = (((size_t)(bb * H_ + h)) * D_ + d) * S_;
#pragma unroll
        for (int r = 0; r < 4; ++r) {
          if (jb + r < nkb) Vp[rb + jb + r] = f2bf(acc[mt][nt][r] + bs[nt]);
        }
      }
    }
  }
}

// ---------------------------------------------------------------------------
// Kernel 2: MFMA flash attention (unchanged).
// ---------------------------------------------------------------------------
__global__ __launch_bounds__(256, 4) void attn_mfma_kernel(
    const u16* __restrict__ QpHi, const u16* __restrict__ QpLo,
    const u16* __restrict__ KpHi, const u16* __restrict__ KpLo,
    const u16* __restrict__ Vp,
    const int* __restrict__ nkArr,
    u16* __restrict__ AOHi)
{
  __shared__ __align__(16) short sm[18432];  // 36,864 B
  short* Khi = sm;                           // [64][72]
  short* Klo = sm + 4608;                    // [64][72]
  short* Vt  = sm + 9216;                    // [64][72] (d-major)
  short* Pb  = sm + 13824;                   // 4 waves x [16][72]

  const int t = threadIdx.x;
  const int w = t >> 6, lane = t & 63;
  const int g = lane >> 4, lc = lane & 15;
  const int bh = blockIdx.y;
  const int b = bh >> 4, hh = bh & 15;
  const int q0 = blockIdx.x * 64;
  const size_t hb = (size_t)bh * S_ * D_;
  const u16* QgH = QpHi + hb;
  const u16* QgL = QpLo + hb;
  const u16* KgH = KpHi + hb;
  const u16* KgL = KpLo + hb;
  const u16* Vg  = Vp + hb;
  short* Pw = Pb + w * 1152;

  const int nk = nkArr[b];
  const int kend = ((nk + 63) >> 6) << 6;    // tiles of 64 compacted keys

  // ---- Q A-frags direct from global (lane lc = q-row, k = 8g..8g+7) ----
  short8 qh[2], ql[2];
  {
    const size_t base = (size_t)(q0 + 16 * w + lc) * D_ + 8 * g;
    qh[0] = *(const short8*)&QgH[base];
    qh[1] = *(const short8*)&QgH[base + 32];
    ql[0] = *(const short8*)&QgL[base];
    ql[1] = *(const short8*)&QgL[base + 32];
  }

  // ones column in B (n=0): lanes with lc==0 hold bf16(1.0) for all k
  short8 ones8 = {0, 0, 0, 0, 0, 0, 0, 0};
  if (lc == 0) {
    const short o = (short)0x3F80;
    ones8 = (short8){o, o, o, o, o, o, o, o};
  }

  f32x4 O[4];
  f32x4 Ol = (f32x4){0.f, 0.f, 0.f, 0.f};
#pragma unroll
  for (int dt = 0; dt < 4; ++dt) O[dt] = (f32x4){0.f, 0.f, 0.f, 0.f};
  float mst[4] = {-INFINITY, -INFINITY, -INFINITY, -INFINITY};

  const int srow = t >> 2, sc16 = (t & 3) * 16;   // staging: 4 threads/row

  // staging prefetch registers (K hi/lo, V)
  short8 kr[2], lr[2], vr[2];
  kr[0] = *(const short8*)&KgH[srow * D_ + sc16];
  kr[1] = *(const short8*)&KgH[srow * D_ + sc16 + 8];
  lr[0] = *(const short8*)&KgL[srow * D_ + sc16];
  lr[1] = *(const short8*)&KgL[srow * D_ + sc16 + 8];
  vr[0] = *(const short8*)&Vg[srow * S_ + sc16];
  vr[1] = *(const short8*)&Vg[srow * S_ + sc16 + 8];

  for (int kt = 0; kt < kend; kt += 64) {
    __syncthreads();                         // previous tile fully consumed
    *(short8*)&Khi[srow * 72 + sc16]     = kr[0];
    *(short8*)&Khi[srow * 72 + sc16 + 8] = kr[1];
    *(short8*)&Klo[srow * 72 + sc16]     = lr[0];
    *(short8*)&Klo[srow * 72 + sc16 + 8] = lr[1];
    *(short8*)&Vt[srow * 72 + sc16]      = vr[0];
    *(short8*)&Vt[srow * 72 + sc16 + 8]  = vr[1];
    __syncthreads();
    if (kt + 64 < kend) {                    // prefetch next tile
      const int kn = kt + 64;
      kr[0] = *(const short8*)&KgH[(kn + srow) * D_ + sc16];
      kr[1] = *(const short8*)&KgH[(kn + srow) * D_ + sc16 + 8];
      lr[0] = *(const short8*)&KgL[(kn + srow) * D_ + sc16];
      lr[1] = *(const short8*)&KgL[(kn + srow) * D_ + sc16 + 8];
      vr[0] = *(const short8*)&Vg[srow * S_ + kn + sc16];
      vr[1] = *(const short8*)&Vg[srow * S_ + kn + sc16 + 8];
    }

    // ---- scores: S[16q x 64k] ----
    f32x4 sc[4];
#pragma unroll
    for (int kt16 = 0; kt16 < 4; ++kt16) {
      const int ko = (16 * kt16 + lc) * 72 + 8 * g;
      const short8 kh0 = *(const short8*)&Khi[ko];
      const short8 kh1 = *(const short8*)&Khi[ko + 32];
      const short8 kl0 = *(const short8*)&Klo[ko];
      const short8 kl1 = *(const short8*)&Klo[ko + 32];
      f32x4 a = {0.f, 0.f, 0.f, 0.f};
      a = __builtin_amdgcn_mfma_f32_16x16x32_bf16(qh[0], kh0, a, 0, 0, 0);
      a = __builtin_amdgcn_mfma_f32_16x16x32_bf16(qh[1], kh1, a, 0, 0, 0);
      a = __builtin_amdgcn_mfma_f32_16x16x32_bf16(qh[0], kl0, a, 0, 0, 0);
      a = __builtin_amdgcn_mfma_f32_16x16x32_bf16(qh[1], kl1, a, 0, 0, 0);
      a = __builtin_amdgcn_mfma_f32_16x16x32_bf16(ql[0], kh0, a, 0, 0, 0);
      a = __builtin_amdgcn_mfma_f32_16x16x32_bf16(ql[1], kh1, a, 0, 0, 0);
      sc[kt16] = a;
    }

    // ---- tail masking: compacted cols >= nk are padding (garbage K) ----
    if (kt + 64 > nk) {
#pragma unroll
      for (int kt16 = 0; kt16 < 4; ++kt16) {
        if (kt + 16 * kt16 + lc >= nk) {
          sc[kt16][0] = -1e20f; sc[kt16][1] = -1e20f;
          sc[kt16][2] = -1e20f; sc[kt16][3] = -1e20f;
        }
      }
    }

    // ---- online max + exp (max butterfly only; sum comes from MFMA) ----
    float al[4];
#pragma unroll
    for (int r = 0; r < 4; ++r) {
      float vv = fmaxf(fmaxf(sc[0][r], sc[1][r]), fmaxf(sc[2][r], sc[3][r]));
      vv = fmaxf(vv, __shfl_xor(vv, 1));
      vv = fmaxf(vv, __shfl_xor(vv, 2));
      vv = fmaxf(vv, __shfl_xor(vv, 4));
      vv = fmaxf(vv, __shfl_xor(vv, 8));
      const float mn = fmaxf(mst[r], vv);
      al[r] = __expf(mst[r] - mn);           // first tile: exp(-inf)=0
      mst[r] = mn;
    }
#pragma unroll
    for (int kt16 = 0; kt16 < 4; ++kt16) {
#pragma unroll
      for (int r = 0; r < 4; ++r)
        sc[kt16][r] = __expf(sc[kt16][r] - mst[r]);
    }
    const f32x4 alv = {al[0], al[1], al[2], al[3]};
    O[0] *= alv; O[1] *= alv; O[2] *= alv; O[3] *= alv;
    Ol *= alv;
    // P: C-layout regs -> bf16 LDS (A-layout source for PV)
#pragma unroll
    for (int kt16 = 0; kt16 < 4; ++kt16) {
#pragma unroll
      for (int r = 0; r < 4; ++r)
        Pw[(4 * g + r) * 72 + 16 * kt16 + lc] = (short)f2bf(sc[kt16][r]);
    }

    // ---- PV + denominator via ones ----
    short8 pa[2];
    pa[0] = *(const short8*)&Pw[lc * 72 + 8 * g];
    pa[1] = *(const short8*)&Pw[lc * 72 + 32 + 8 * g];
    Ol = __builtin_amdgcn_mfma_f32_16x16x32_bf16(pa[0], ones8, Ol, 0, 0, 0);
    Ol = __builtin_amdgcn_mfma_f32_16x16x32_bf16(pa[1], ones8, Ol, 0, 0, 0);
#pragma unroll
    for (int dt = 0; dt < 4; ++dt) {
      const int vo = (16 * dt + lc) * 72 + 8 * g;
      const short8 vb0 = *(const short8*)&Vt[vo];
      const short8 vb1 = *(const short8*)&Vt[vo + 32];
      O[dt] = __builtin_amdgcn_mfma_f32_16x16x32_bf16(pa[0], vb0, O[dt], 0, 0, 0);
      O[dt] = __builtin_amdgcn_mfma_f32_16x16x32_bf16(pa[1], vb1, O[dt], 0, 0, 0);
    }
  }

  // ---- epilogue: broadcast denominator (col 0 on lanes lc==0), normalize ----
#pragma unroll
  for (int r = 0; r < 4; ++r) {
    const float lv = __shfl(Ol[r], lane & 48);
    const float lir = 1.0f / lv;
    const int qrow = q0 + 16 * w + 4 * g + r;
    const size_t rowb = (size_t)(b * S_ + qrow) * E_ + hh * 64;
#pragma unroll
    for (int dt = 0; dt < 4; ++dt)
      AOHi[rowb + dt * 16 + lc] = f2bf(O[dt][r] * lir);
  }
}

// ---------------------------------------------------------------------------
// Kernel 3: output projection. v4: 64x64 tiles (grid 64x16 = 1024 blocks =
// 4 blocks/CU), distance-2 register prefetch, A & B LDS-staged, two
// __syncthreads per 32-k step. 4 waves (2m x 2n), wave = 32x32 (acc[2][2]).
// ---------------------------------------------------------------------------
__global__ __launch_bounds__(256) void gemm_out_kernel(
    const u16* __restrict__ AHi,
    const u16* __restrict__ WHi,
    const float* __restrict__ bias, float* __restrict__ out)
{
  __shared__ __align__(16) short smem[5120];   // A[64][40] + B[64][40]
  short* Ah = smem;
  short* Bh = smem + 2560;

  const int t = threadIdx.x;
  const int m0 = blockIdx.x * 64;
  const int n0 = blockIdx.y * 64;
  const int w = t >> 6, lane = t & 63;
  const int g = lane >> 4, lc = lane & 15;
  const int wm = w & 1, wn = w >> 1;
  const int sr = t >> 2, sc = (t & 3) * 8;     // staging: 4 thr/row, 8 u16

  const u16* Ahb = AHi + (size_t)(m0 + sr) * E_ + sc;
  const u16* Bhb = WHi + (size_t)(n0 + sr) * E_ + sc;

  f32x4 acc[2][2];
#pragma unroll
  for (int i = 0; i < 2; ++i)
#pragma unroll
    for (int j = 0; j < 2; ++j) acc[i][j] = (f32x4){0.f, 0.f, 0.f, 0.f};

  short8 arP[2], brP[2];
  arP[0] = *(const short8*)(Ahb);
  arP[1] = *(const short8*)(Ahb + 32);
  brP[0] = *(const short8*)(Bhb);
  brP[1] = *(const short8*)(Bhb + 32);

#pragma unroll 2
  for (int k0 = 0; k0 < E_; k0 += 32) {
    const int p = (k0 >> 5) & 1;
    __syncthreads();
    *(short8*)&Ah[sr * 40 + sc] = arP[p];
    *(short8*)&Bh[sr * 40 + sc] = brP[p];
    __syncthreads();
    {
      const int kk = (k0 + 64) & (E_ - 1);
      arP[p] = *(const short8*)(Ahb + kk);
      brP[p] = *(const short8*)(Bhb + kk);
    }

    short8 ah[2], bh[2];
#pragma unroll
    for (int mt = 0; mt < 2; ++mt)
      ah[mt] = *(const short8*)&Ah[(wm * 32 + mt * 16 + lc) * 40 + g * 8];
#pragma unroll
    for (int nt = 0; nt < 2; ++nt)
      bh[nt] = *(const short8*)&Bh[(wn * 32 + nt * 16 + lc) * 40 + g * 8];
#pragma unroll
    for (int mt = 0; mt < 2; ++mt)
#pragma unroll
      for (int nt = 0; nt < 2; ++nt)
        acc[mt][nt] = __builtin_amdgcn_mfma_f32_16x16x32_bf16(ah[mt], bh[nt], acc[mt][nt], 0, 0, 0);
  }

  float bs[2];
#pragma unroll
  for (int nt = 0; nt < 2; ++nt) bs[nt] = bias[n0 + wn * 32 + nt * 16 + lc];
#pragma unroll
  for (int nt = 0; nt < 2; ++nt) {
    const int nc = n0 + wn * 32 + nt * 16 + lc;
#pragma unroll
    for (int mt = 0; mt < 2; ++mt) {
#pragma unroll
      for (int r = 0; r < 4; ++r) {
        const int mrow = m0 + wm * 32 + mt * 16 + g * 4 + r;
        out[(size_t)mrow * E_ + nc] = acc[mt][nt][r] + bs[nt];
      }
    }
  }
}

// ---------------------------------------------------------------------------
extern "C" void kernel_launch(void* const* d_in, const int* in_sizes, int n_in,
                              void* d_out, int out_size, void* d_ws, size_t ws_size,
                              hipStream_t stream) {
  const float* q    = (const float*)d_in[0];
  const float* k    = (const float*)d_in[1];
  const float* v    = (const float*)d_in[2];
  const int*   mask = (const int*)d_in[3];
  const float* Wqkv = (const float*)d_in[4];
  const float* bqkv = (const float*)d_in[5];
  const float* Wout = (const float*)d_in[6];
  const float* bout = (const float*)d_in[7];
  float* out = (float*)d_out;

  // Workspace layout (64 MB).
  char* wsb = (char*)d_ws;
  u16* WqkvHi = (u16*)(wsb + 0);          //  6 MB
  u16* WqkvLo = (u16*)(wsb + 6291456);    //  6 MB
  u16* WoutHi = (u16*)(wsb + 12582912);   //  2 MB
  // WoutLo region (2 MB at 14680064) is scratch: split writes it, then the
  // scan kernel reuses the space for opos/nk (stream-ordered, safe).
  int* Opos   = (int*)(wsb + 14680064);   // 16 KB (B*S ints)
  int* Nk     = (int*)(wsb + 14680064 + 16384);  // 8 B
  u16* WoutLo = (u16*)(wsb + 14680064);   // (written then overwritten, unused)
  u16* QpHi   = (u16*)(wsb + 16777216);   //  8 MB
  u16* QpLo   = (u16*)(wsb + 25165824);   //  8 MB
  u16* KpHi   = (u16*)(wsb + 33554432);   //  8 MB
  u16* KpLo   = (u16*)(wsb + 41943040);   //  8 MB
  u16* Vp     = (u16*)(wsb + 50331648);   //  8 MB
  u16* AOHi   = (u16*)(wsb + 58720256);   //  8 MB

  hipLaunchKernelGGL(split_f32_kernel, dim3(3072), dim3(256), 0, stream,
                     Wqkv, WqkvHi, WqkvLo, 786432);
  hipLaunchKernelGGL(split_f32_kernel, dim3(1024), dim3(256), 0, stream,
                     Wout, WoutHi, WoutLo, 262144);
  hipLaunchKernelGGL(mask_scan_kernel, dim3(B_), dim3(256), 0, stream,
                     mask, Opos, Nk);
  // zero V so padded tail columns (>= nk) contribute exact 0 in PV
  hipMemsetAsync(Vp, 0, 8388608, stream);
  hipLaunchKernelGGL(gemm_qkv_kernel, dim3(M_ / 128, 48), dim3(256), 0, stream,
                     q, k, v, WqkvHi, WqkvLo, bqkv, Opos, Nk,
                     QpHi, QpLo, KpHi, KpLo, Vp);
  hipLaunchKernelGGL(attn_mfma_kernel, dim3(S_ / 64, B_ * H_), dim3(256), 0, stream,
                     QpHi, QpLo, KpHi, KpLo, Vp, Nk, AOHi);
  hipLaunchKernelGGL(gemm_out_kernel, dim3(M_ / 64, E_ / 64), dim3(256), 0, stream,
                     AOHi, WoutHi, bout, out);
}